// Round 1
// baseline (785.184 us; speedup 1.0000x reference)
//
#include <hip/hip_runtime.h>

// BaseTextureDiffusion: out[b,c,y,x] = sum_k w[b,c,k,y,x] * latent_pad[b,c,y+i,x+j]
// B=2 C=24 H=W=256 R=7 (replicate pad 3). Memory-bound on the 616 MB weights stream.

constexpr int Hh = 256, Ww = 256, Rr = 7, PAD = 3;
constexpr int TILE_W = 64, TILE_H = 16;
constexpr int LW  = TILE_W + 2 * PAD;   // 70 valid cols
constexpr int LWP = 72;                 // padded row stride (x4B = 288 B, 16B-aligned rows)
constexpr int LH  = TILE_H + 2 * PAD;   // 22 rows
constexpr int TILES_X = Ww / TILE_W;    // 4
constexpr int TILES_Y = Hh / TILE_H;    // 16
constexpr int TILES_PER_PLANE = TILES_X * TILES_Y;  // 64

__global__ __launch_bounds__(256) void diffusion_kernel(
    const float* __restrict__ latent,
    const float* __restrict__ weights,
    float* __restrict__ out)
{
    __shared__ __align__(16) float lds[LH * LWP];

    const int block = blockIdx.x;
    const int plane = block / TILES_PER_PLANE;          // b*C + c
    const int t     = block % TILES_PER_PLANE;
    const int ty0   = (t / TILES_X) * TILE_H;
    const int tx0   = (t % TILES_X) * TILE_W;

    const float* lat  = latent  + (size_t)plane * Hh * Ww;
    const float* wgt  = weights + (size_t)plane * (Rr * Rr) * Hh * Ww;
    float*       optr = out     + (size_t)plane * Hh * Ww;

    // Stage latent tile with replicate clamping (halo = 3 each side).
    for (int idx = threadIdx.x; idx < LH * LW; idx += 256) {
        const int ly = idx / LW;
        const int lx = idx - ly * LW;
        const int gy = min(max(ty0 + ly - PAD, 0), Hh - 1);
        const int gx = min(max(tx0 + lx - PAD, 0), Ww - 1);
        lds[ly * LWP + lx] = lat[gy * Ww + gx];
    }
    __syncthreads();

    // Thread -> 4 consecutive x pixels. tx in [0,16), ty in [0,16).
    const int tx = threadIdx.x & 15;
    const int ty = threadIdx.x >> 4;
    const int x  = tx0 + 4 * tx;
    const int y  = ty0 + ty;

    const float* wbase = wgt + (size_t)y * Ww + x;

    float4 acc = make_float4(0.f, 0.f, 0.f, 0.f);

    #pragma unroll
    for (int i = 0; i < Rr; ++i) {
        // 10 consecutive floats from the LDS row (16B-aligned start).
        const float* lrow = &lds[(ty + i) * LWP + 4 * tx];
        const float4 a = *(const float4*)(lrow);
        const float4 b = *(const float4*)(lrow + 4);
        const float2 c = *(const float2*)(lrow + 8);
        const float r[10] = {a.x, a.y, a.z, a.w, b.x, b.y, b.z, b.w, c.x, c.y};

        #pragma unroll
        for (int j = 0; j < Rr; ++j) {
            const int k = i * Rr + j;
            const float4 w4 = *(const float4*)(wbase + (size_t)k * (Hh * Ww));
            acc.x += w4.x * r[j + 0];
            acc.y += w4.y * r[j + 1];
            acc.z += w4.z * r[j + 2];
            acc.w += w4.w * r[j + 3];
        }
    }

    *(float4*)(optr + (size_t)y * Ww + x) = acc;
}

extern "C" void kernel_launch(void* const* d_in, const int* in_sizes, int n_in,
                              void* d_out, int out_size, void* d_ws, size_t ws_size,
                              hipStream_t stream) {
    const float* latent  = (const float*)d_in[0];
    const float* weights = (const float*)d_in[1];
    // d_in[2] = window_size (scalar int, fixed at 7) -- compiled in.
    float* out = (float*)d_out;

    const int B = 2, C = 24;
    const int nblocks = B * C * TILES_PER_PLANE;  // 3072
    diffusion_kernel<<<nblocks, 256, 0, stream>>>(latent, weights, out);
}

// Round 3
// 752.888 us; speedup vs baseline: 1.0429x; 1.0429x over previous
//
#include <hip/hip_runtime.h>

// BaseTextureDiffusion: out[b,c,y,x] = sum_k w[b,c,k,y,x] * latent_pad[b,c,y+i,x+j]
// B=2 C=24 H=W=256 R=7 (replicate pad 3). Memory-bound on the 616 MB weights stream.
// Tile = full row width (256) x 4 rows: each wave's weight load is one contiguous
// 1 KB segment (64 lanes x float4) -- ideal coalescing granularity.

typedef float fx4 __attribute__((ext_vector_type(4)));   // nontemporal builtins need a true vector type

constexpr int Hh = 256, Ww = 256, Rr = 7, PAD = 3;
constexpr int TILE_H = 4;
constexpr int LW  = Ww + 2 * PAD;       // 262 valid cols (full width + halo)
constexpr int LWP = 264;                // padded stride, 264*4B multiple of 16
constexpr int LH  = TILE_H + 2 * PAD;   // 10 rows
constexpr int TILES_Y = Hh / TILE_H;    // 64
constexpr int PLANES  = 48;             // B*C

__global__ __launch_bounds__(256) void diffusion_kernel(
    const float* __restrict__ latent,
    const float* __restrict__ weights,
    float* __restrict__ out)
{
    __shared__ __align__(16) float lds[LH * LWP];   // 10.56 KB

    const int bid   = blockIdx.x;
    const int plane = bid / TILES_Y;                // b*C + c (consecutive bids share plane)
    const int ty0   = (bid % TILES_Y) * TILE_H;

    const float* lat  = latent  + (size_t)plane * Hh * Ww;
    const float* wgt  = weights + (size_t)plane * (Rr * Rr) * Hh * Ww;
    float*       optr = out     + (size_t)plane * Hh * Ww;

    // Stage latent rows [ty0-3, ty0+TILE_H+3) with replicate clamping.
    for (int idx = threadIdx.x; idx < LH * LW; idx += 256) {
        const int ly = idx / LW;
        const int lx = idx - ly * LW;
        const int gy = min(max(ty0 + ly - PAD, 0), Hh - 1);
        const int gx = min(max(lx - PAD, 0), Ww - 1);
        lds[ly * LWP + lx] = lat[gy * Ww + gx];
    }
    __syncthreads();

    // Wave = one full output row: tx in [0,64) covers x = 4*tx, ty in [0,4).
    const int tx = threadIdx.x & 63;
    const int ty = threadIdx.x >> 6;
    const int x  = 4 * tx;
    const int y  = ty0 + ty;

    const float* wbase = wgt + (size_t)y * Ww + x;

    fx4 acc = {0.f, 0.f, 0.f, 0.f};

    #pragma unroll
    for (int i = 0; i < Rr; ++i) {
        // 10 consecutive floats from the LDS row (16B-aligned start).
        const float* lrow = &lds[(ty + i) * LWP + x];
        const float4 a = *(const float4*)(lrow);
        const float4 b = *(const float4*)(lrow + 4);
        const float2 c = *(const float2*)(lrow + 8);
        const float r[10] = {a.x, a.y, a.z, a.w, b.x, b.y, b.z, b.w, c.x, c.y};

        #pragma unroll
        for (int j = 0; j < Rr; ++j) {
            const int k = i * Rr + j;
            const fx4 w4 = __builtin_nontemporal_load(
                (const fx4*)(wbase + (size_t)k * (Hh * Ww)));
            acc.x += w4.x * r[j + 0];
            acc.y += w4.y * r[j + 1];
            acc.z += w4.z * r[j + 2];
            acc.w += w4.w * r[j + 3];
        }
    }

    __builtin_nontemporal_store(acc, (fx4*)(optr + (size_t)y * Ww + x));
}

extern "C" void kernel_launch(void* const* d_in, const int* in_sizes, int n_in,
                              void* d_out, int out_size, void* d_ws, size_t ws_size,
                              hipStream_t stream) {
    const float* latent  = (const float*)d_in[0];
    const float* weights = (const float*)d_in[1];
    // d_in[2] = window_size (scalar int, fixed at 7) -- compiled in.
    float* out = (float*)d_out;

    const int nblocks = PLANES * TILES_Y;  // 3072
    diffusion_kernel<<<nblocks, 256, 0, stream>>>(latent, weights, out);
}